// Round 1
// baseline (993.666 us; speedup 1.0000x reference)
//
#include <hip/hip_runtime.h>

#define DIM 64
#define NEG 0.2f
#define SB 1024

// ---------------- out = b_concur + b_upd + b_side (broadcast per column) ----------------
__global__ void init_out(float* __restrict__ out,
                         const float* __restrict__ b0, const float* __restrict__ b1,
                         const float* __restrict__ b2, int n) {
  int i = blockIdx.x * blockDim.x + threadIdx.x;
  if (i < n * DIM) {
    int c = i & (DIM - 1);
    out[i] = b0[c] + b1[c] + b2[c];
  }
}

// ---------------- feat = x @ W ; el = feat.al ; er = feat.ar ----------------
// block (64,4): threadIdx.x = output column (one wave per row), threadIdx.y = row-in-block
__global__ __launch_bounds__(256) void proj_kernel(
    const float* __restrict__ x, const float* __restrict__ W,
    const float* __restrict__ al, const float* __restrict__ ar,
    float* __restrict__ feat, float* __restrict__ el, float* __restrict__ er, int n) {
  __shared__ float Ws[DIM][DIM];
  int tid = threadIdx.y * 64 + threadIdx.x;
  for (int i = tid; i < DIM * DIM; i += 256) Ws[i >> 6][i & 63] = W[i];
  __syncthreads();

  int row = blockIdx.x * 4 + threadIdx.y;
  if (row >= n) return;
  int lane = threadIdx.x;
  const float* xr = x + (size_t)row * DIM;

  float acc = 0.f;
#pragma unroll
  for (int k = 0; k < DIM; ++k) acc = fmaf(xr[k], Ws[k][lane], acc);  // xr[k] wave-broadcast

  feat[(size_t)row * DIM + lane] = acc;

  float pl = acc * al[lane];
  float pr = acc * ar[lane];
#pragma unroll
  for (int o = 32; o > 0; o >>= 1) {
    pl += __shfl_xor(pl, o, 64);
    pr += __shfl_xor(pr, o, 64);
  }
  if (lane == 0) { el[row] = pl; er[row] = pr; }
}

// ---------------- CSR build: histogram, scan (3-level), scatter src ids ----------------
__global__ void count_kernel(const int* __restrict__ dst, int* __restrict__ cnt, int e) {
  int i = blockIdx.x * blockDim.x + threadIdx.x;
  if (i < e) atomicAdd(&cnt[dst[i]], 1);
}

__global__ __launch_bounds__(SB) void scan1(const int* __restrict__ cnt, int* __restrict__ off,
                                            int* __restrict__ bsum, int n) {
  __shared__ int sm[SB];
  int i = blockIdx.x * SB + threadIdx.x;
  int v = (i < n) ? cnt[i] : 0;
  sm[threadIdx.x] = v;
  __syncthreads();
  for (int o = 1; o < SB; o <<= 1) {
    int t = ((int)threadIdx.x >= o) ? sm[threadIdx.x - o] : 0;
    __syncthreads();
    sm[threadIdx.x] += t;
    __syncthreads();
  }
  if (i < n) off[i + 1] = sm[threadIdx.x];          // inclusive within block
  if (threadIdx.x == SB - 1) bsum[blockIdx.x] = sm[SB - 1];
}

__global__ __launch_bounds__(SB) void scan2(int* __restrict__ bsum, int nb) {
  __shared__ int sm[SB];
  int v = ((int)threadIdx.x < nb) ? bsum[threadIdx.x] : 0;
  sm[threadIdx.x] = v;
  __syncthreads();
  for (int o = 1; o < SB; o <<= 1) {
    int t = ((int)threadIdx.x >= o) ? sm[threadIdx.x - o] : 0;
    __syncthreads();
    sm[threadIdx.x] += t;
    __syncthreads();
  }
  if ((int)threadIdx.x < nb) bsum[threadIdx.x] = sm[threadIdx.x] - v;  // exclusive
}

__global__ __launch_bounds__(SB) void scan3(int* __restrict__ off, const int* __restrict__ bsum,
                                            int n) {
  int i = blockIdx.x * SB + threadIdx.x;
  if (i < n) off[i + 1] += bsum[blockIdx.x];
  if (i == 0) off[0] = 0;
}

__global__ void scatter_kernel(const int* __restrict__ src, const int* __restrict__ dst,
                               const int* __restrict__ off, int* __restrict__ cur,
                               int* __restrict__ bucket, int e) {
  int i = blockIdx.x * blockDim.x + threadIdx.x;
  if (i < e) {
    int d = dst[i];
    int p = atomicAdd(&cur[d], 1);
    bucket[off[d] + p] = src[i];  // store SRC node id directly; dst implicit in bucket
  }
}

// ---------------- pull-based GAT aggregation: one wave per destination node ----------------
__global__ __launch_bounds__(256) void gat_agg(
    const float* __restrict__ feat, const float* __restrict__ el, const float* __restrict__ er,
    const int* __restrict__ off, const int* __restrict__ bucket,
    float* __restrict__ out, int n) {
  int wv = (blockIdx.x * blockDim.x + threadIdx.x) >> 6;
  int lane = threadIdx.x & 63;
  if (wv >= n) return;
  int beg = off[wv], end = off[wv + 1];
  if (beg == end) return;  // empty segment: reference contributes only bias
  float erd = er[wv];

  // pass 1: segment max (edges distributed across lanes, then wave-reduce)
  float lmax = -3.4e38f;
  for (int i = beg + lane; i < end; i += 64) {
    float v = el[bucket[i]] + erd;
    v = v > 0.f ? v : NEG * v;
    lmax = fmaxf(lmax, v);
  }
#pragma unroll
  for (int o = 32; o > 0; o >>= 1) lmax = fmaxf(lmax, __shfl_xor(lmax, o, 64));

  // pass 2: exp-sum + weighted feature accumulation (all lanes walk all edges;
  // bucket[i]/el[sn] are wave-uniform -> HW broadcast; feat gather is coalesced 256B)
  float s = 0.f, acc = 0.f;
  for (int i = beg; i < end; ++i) {
    int sn = bucket[i];
    float v = el[sn] + erd;
    v = v > 0.f ? v : NEG * v;
    float a = __expf(v - lmax);
    s += a;
    acc = fmaf(a, feat[(size_t)sn * DIM + lane], acc);
  }
  out[(size_t)wv * DIM + lane] += acc / s;
}

extern "C" void kernel_launch(void* const* d_in, const int* in_sizes, int n_in,
                              void* d_out, int out_size, void* d_ws, size_t ws_size,
                              hipStream_t stream) {
  const float* x = (const float*)d_in[0];
  const int n = in_sizes[0] / DIM;
  float* out = (float*)d_out;

  // workspace carve (all fully re-initialized every call; harness poisons ws)
  char* w = (char*)d_ws;
  float* feat = (float*)w;  w += (size_t)n * DIM * sizeof(float);
  float* el   = (float*)w;  w += (size_t)n * sizeof(float);
  float* er   = (float*)w;  w += (size_t)n * sizeof(float);
  int* cnt    = (int*)w;    w += (size_t)n * sizeof(int);   // cnt & cur contiguous:
  int* cur    = (int*)w;    w += (size_t)n * sizeof(int);   // one memset covers both
  int* off    = (int*)w;    w += (size_t)(n + 1) * sizeof(int);
  int* bsum   = (int*)w;    w += (size_t)SB * sizeof(int);
  int* bucket = (int*)w;

  init_out<<<(n * DIM + 255) / 256, 256, 0, stream>>>(
      out, (const float*)d_in[6], (const float*)d_in[12], (const float*)d_in[18], n);

  for (int r = 0; r < 3; ++r) {
    const int base = 1 + r * 6;  // dict order: x, then per-rel {src,dst,W,al,ar,b}
    const int* srcp = (const int*)d_in[base + 0];
    const int* dstp = (const int*)d_in[base + 1];
    const float* W  = (const float*)d_in[base + 2];
    const float* al = (const float*)d_in[base + 3];
    const float* ar = (const float*)d_in[base + 4];
    const int e = in_sizes[base];

    proj_kernel<<<(n + 3) / 4, dim3(64, 4), 0, stream>>>(x, W, al, ar, feat, el, er, n);

    hipMemsetAsync(cnt, 0, (size_t)2 * n * sizeof(int), stream);  // cnt + cur
    count_kernel<<<(e + 255) / 256, 256, 0, stream>>>(dstp, cnt, e);

    const int nb = (n + SB - 1) / SB;  // 98 blocks for N=100000 (fits scan2's single block)
    scan1<<<nb, SB, 0, stream>>>(cnt, off, bsum, n);
    scan2<<<1, SB, 0, stream>>>(bsum, nb);
    scan3<<<nb, SB, 0, stream>>>(off, bsum, n);

    scatter_kernel<<<(e + 255) / 256, 256, 0, stream>>>(srcp, dstp, off, cur, bucket, e);

    gat_agg<<<(n + 3) / 4, 256, 0, stream>>>(feat, el, er, off, bucket, out, n);
  }
}

// Round 2
// 806.106 us; speedup vs baseline: 1.2327x; 1.2327x over previous
//
#include <hip/hip_runtime.h>

#define DIM 64
#define NEG 0.2f
#define SB 1024

// ---------------- feat = x @ W ; el = feat.al ; er = feat.ar ----------------
// block (64,4): threadIdx.x = output column (one wave per row)
__global__ __launch_bounds__(256) void proj_kernel(
    const float* __restrict__ x, const float* __restrict__ W,
    const float* __restrict__ al, const float* __restrict__ ar,
    float* __restrict__ feat, float* __restrict__ el, float* __restrict__ er, int n) {
  __shared__ float Ws[DIM][DIM];
  int tid = threadIdx.y * 64 + threadIdx.x;
  for (int i = tid; i < DIM * DIM; i += 256) Ws[i >> 6][i & 63] = W[i];
  __syncthreads();

  int row = blockIdx.x * 4 + threadIdx.y;
  if (row >= n) return;
  int lane = threadIdx.x;
  const float* xr = x + (size_t)row * DIM;

  float acc = 0.f;
#pragma unroll
  for (int k = 0; k < DIM; ++k) acc = fmaf(xr[k], Ws[k][lane], acc);  // xr[k] wave-broadcast

  feat[(size_t)row * DIM + lane] = acc;

  float pl = acc * al[lane];
  float pr = acc * ar[lane];
#pragma unroll
  for (int o = 32; o > 0; o >>= 1) {
    pl += __shfl_xor(pl, o, 64);
    pr += __shfl_xor(pr, o, 64);
  }
  if (lane == 0) { el[row] = pl; er[row] = pr; }
}

// ---------------- out = b0+b1+b2 (lean-path init) ----------------
__global__ void init_out(float* __restrict__ out,
                         const float* __restrict__ b0, const float* __restrict__ b1,
                         const float* __restrict__ b2, int n) {
  int i = blockIdx.x * blockDim.x + threadIdx.x;
  if (i < n * DIM) {
    int c = i & (DIM - 1);
    out[i] = b0[c] + b1[c] + b2[c];
  }
}

// ---------------- CSR build ----------------
__global__ void count_kernel(const int* __restrict__ dst, int* __restrict__ cnt, int e) {
  int i = blockIdx.x * blockDim.x + threadIdx.x;
  if (i < e) atomicAdd(&cnt[dst[i]], 1);
}

__global__ __launch_bounds__(SB) void scan1(const int* __restrict__ cnt, int* __restrict__ off,
                                            int* __restrict__ bsum, int n) {
  __shared__ int sm[SB];
  int i = blockIdx.x * SB + threadIdx.x;
  int v = (i < n) ? cnt[i] : 0;
  sm[threadIdx.x] = v;
  __syncthreads();
  for (int o = 1; o < SB; o <<= 1) {
    int t = ((int)threadIdx.x >= o) ? sm[threadIdx.x - o] : 0;
    __syncthreads();
    sm[threadIdx.x] += t;
    __syncthreads();
  }
  if (i < n) off[i + 1] = sm[threadIdx.x];  // inclusive within block
  if (threadIdx.x == SB - 1) bsum[blockIdx.x] = sm[SB - 1];
}

__global__ __launch_bounds__(SB) void scan2(int* __restrict__ bsum, int nb) {
  __shared__ int sm[SB];
  int v = ((int)threadIdx.x < nb) ? bsum[threadIdx.x] : 0;
  sm[threadIdx.x] = v;
  __syncthreads();
  for (int o = 1; o < SB; o <<= 1) {
    int t = ((int)threadIdx.x >= o) ? sm[threadIdx.x - o] : 0;
    __syncthreads();
    sm[threadIdx.x] += t;
    __syncthreads();
  }
  if ((int)threadIdx.x < nb) bsum[threadIdx.x] = sm[threadIdx.x] - v;  // exclusive
}

__global__ __launch_bounds__(SB) void scan3(int* __restrict__ off, const int* __restrict__ bsum,
                                            int n) {
  int i = blockIdx.x * SB + threadIdx.x;
  if (i < n) off[i + 1] += bsum[blockIdx.x];
  if (i == 0) off[0] = 0;
}

// scatter src id + precomputed leaky-relu logit into the dst-CSR bucket
__global__ void scatter_pair(const int* __restrict__ src, const int* __restrict__ dst,
                             const float* __restrict__ el, const float* __restrict__ er,
                             const int* __restrict__ off_r, int* __restrict__ cur_r,
                             int2* __restrict__ pairs, int ebase, int e) {
  int i = blockIdx.x * blockDim.x + threadIdx.x;
  if (i < e) {
    int d = dst[i], sN = src[i];
    float v = el[sN] + er[d];  // el/er are 400 KB: L2-resident gathers
    v = v > 0.f ? v : NEG * v;
    int p = atomicAdd(&cur_r[d], 1);
    int2 pr;
    pr.x = sN;
    pr.y = __float_as_int(v);
    pairs[off_r[d] + p - ebase] = pr;
  }
}

// ---------------- per-node softmax + weighted aggregation (one wave per node) ----------------
__device__ __forceinline__ float rel_contrib(const float* __restrict__ feat,
                                             const int2* __restrict__ pairs,
                                             int beg, int end, int lane) {
  int deg = end - beg;
  if (deg <= 0) return 0.f;
  float acc = 0.f, s;
  if (deg <= 64) {
    // lane-parallel: lane l owns edge beg+l; one coalesced 8B load round-trip
    int2 pr = (lane < deg) ? pairs[beg + lane] : make_int2(0, 0xFF800000);  // -inf
    float v = __int_as_float(pr.y);
    float m = v;
#pragma unroll
    for (int o = 32; o > 0; o >>= 1) m = fmaxf(m, __shfl_xor(m, o, 64));
    float a = (lane < deg) ? __expf(v - m) : 0.f;
    float t = a;
#pragma unroll
    for (int o = 32; o > 0; o >>= 1) t += __shfl_xor(t, o, 64);
    s = t;
    // broadcast loop: per edge only a shfl pair + one independent coalesced 256B gather
    for (int j = 0; j < deg; ++j) {
      int sn = __shfl(pr.x, j, 64);
      float aj = __shfl(a, j, 64);
      acc = fmaf(aj, feat[(size_t)sn * DIM + lane], acc);
    }
  } else {
    // rare fallback: chunked two-pass
    float m = -3.4e38f;
    for (int i = beg + lane; i < end; i += 64) m = fmaxf(m, __int_as_float(pairs[i].y));
#pragma unroll
    for (int o = 32; o > 0; o >>= 1) m = fmaxf(m, __shfl_xor(m, o, 64));
    s = 0.f;
    for (int base = beg; base < end; base += 64) {
      int cm = min(64, end - base);
      int2 pr = (lane < cm) ? pairs[base + lane] : make_int2(0, 0);
      float a = (lane < cm) ? __expf(__int_as_float(pr.y) - m) : 0.f;
      float t = a;
#pragma unroll
      for (int o = 32; o > 0; o >>= 1) t += __shfl_xor(t, o, 64);
      s += t;
      for (int j = 0; j < cm; ++j) {
        int sn = __shfl(pr.x, j, 64);
        float aj = __shfl(a, j, 64);
        acc = fmaf(aj, feat[(size_t)sn * DIM + lane], acc);
      }
    }
  }
  return acc / s;
}

__global__ __launch_bounds__(256) void agg3(
    const float* __restrict__ f0, const float* __restrict__ f1, const float* __restrict__ f2,
    const int* __restrict__ off, const int2* __restrict__ pairs,
    const float* __restrict__ b0, const float* __restrict__ b1, const float* __restrict__ b2,
    float* __restrict__ out, int n) {
  int wv = (blockIdx.x * blockDim.x + threadIdx.x) >> 6;
  int lane = threadIdx.x & 63;
  if (wv >= n) return;
  float r = b0[lane] + b1[lane] + b2[lane];
  r += rel_contrib(f0, pairs, off[wv], off[wv + 1], lane);
  r += rel_contrib(f1, pairs, off[n + wv], off[n + wv + 1], lane);
  r += rel_contrib(f2, pairs, off[2 * n + wv], off[2 * n + wv + 1], lane);
  out[(size_t)wv * DIM + lane] = r;
}

__global__ __launch_bounds__(256) void agg1(
    const float* __restrict__ feat, const int* __restrict__ off_r,
    const int2* __restrict__ pairs, int ebase, float* __restrict__ out, int n) {
  int wv = (blockIdx.x * blockDim.x + threadIdx.x) >> 6;
  int lane = threadIdx.x & 63;
  if (wv >= n) return;
  float c = rel_contrib(feat, pairs, off_r[wv] - ebase, off_r[wv + 1] - ebase, lane);
  out[(size_t)wv * DIM + lane] += c;
}

static inline char* alignup(char* p) {
  return (char*)(((uintptr_t)p + 255) & ~(uintptr_t)255);
}

extern "C" void kernel_launch(void* const* d_in, const int* in_sizes, int n_in,
                              void* d_out, int out_size, void* d_ws, size_t ws_size,
                              hipStream_t stream) {
  const float* x = (const float*)d_in[0];
  const int n = in_sizes[0] / DIM;
  const int m = 3 * n;
  float* out = (float*)d_out;

  const int eN[3] = {in_sizes[1], in_sizes[7], in_sizes[13]};
  const int eTot = eN[0] + eN[1] + eN[2];
  int eMax = eN[0];
  if (eN[1] > eMax) eMax = eN[1];
  if (eN[2] > eMax) eMax = eN[2];

  const size_t featB = (size_t)n * DIM * sizeof(float);
  const size_t nB = (size_t)n * sizeof(float);

  // fused-path footprint: 3 feats + el/er[3n] + cnt/cur[3n] + off[3n+1] + bsum + pairs[eTot]
  const size_t needFused = 3 * featB + 2 * 3 * nB + 2 * 3 * nB + (size_t)(m + 2) * 4 +
                           SB * 4 + (size_t)eTot * 8 + 8 * 256;
  const bool fused = ws_size >= needFused;

  char* w = (char*)d_ws;
  float* feat = (float*)w;            w += fused ? 3 * featB : featB;  w = alignup(w);
  float* el = (float*)w;              w += fused ? 3 * nB : nB;        w = alignup(w);
  float* er = (float*)w;              w += fused ? 3 * nB : nB;        w = alignup(w);
  int* cnt = (int*)w;                 w += 3 * nB;                     // cnt+cur contiguous
  int* cur = (int*)w;                 w += 3 * nB;                     w = alignup(w);
  int* off = (int*)w;                 w += (size_t)(m + 1) * 4;        w = alignup(w);
  int* bsum = (int*)w;                w += SB * 4;                     w = alignup(w);
  int2* pairs = (int2*)w;

  const int nb = (m + SB - 1) / SB;  // 293 blocks for n=100000; scan2 handles nb<=1024

  // histogram + offsets for all 3 relations in one scan pass
  hipMemsetAsync(cnt, 0, (size_t)2 * m * sizeof(int), stream);
  for (int r = 0; r < 3; ++r)
    count_kernel<<<(eN[r] + 255) / 256, 256, 0, stream>>>((const int*)d_in[2 + 6 * r],
                                                          cnt + (size_t)r * n, eN[r]);
  scan1<<<nb, SB, 0, stream>>>(cnt, off, bsum, m);
  scan2<<<1, SB, 0, stream>>>(bsum, nb);
  scan3<<<nb, SB, 0, stream>>>(off, bsum, m);

  if (fused) {
    for (int r = 0; r < 3; ++r) {
      const int base = 1 + r * 6;
      proj_kernel<<<(n + 3) / 4, dim3(64, 4), 0, stream>>>(
          x, (const float*)d_in[base + 2], (const float*)d_in[base + 3],
          (const float*)d_in[base + 4], feat + (size_t)r * n * DIM, el + (size_t)r * n,
          er + (size_t)r * n, n);
    }
    for (int r = 0; r < 3; ++r) {
      const int base = 1 + r * 6;
      scatter_pair<<<(eN[r] + 255) / 256, 256, 0, stream>>>(
          (const int*)d_in[base], (const int*)d_in[base + 1], el + (size_t)r * n,
          er + (size_t)r * n, off + (size_t)r * n, cur + (size_t)r * n, pairs, 0, eN[r]);
    }
    agg3<<<(n + 3) / 4, 256, 0, stream>>>(
        feat, feat + (size_t)n * DIM, feat + (size_t)2 * n * DIM, off, pairs,
        (const float*)d_in[6], (const float*)d_in[12], (const float*)d_in[18], out, n);
  } else {
    init_out<<<(n * DIM + 255) / 256, 256, 0, stream>>>(
        out, (const float*)d_in[6], (const float*)d_in[12], (const float*)d_in[18], n);
    int ebase = 0;
    for (int r = 0; r < 3; ++r) {
      const int base = 1 + r * 6;
      proj_kernel<<<(n + 3) / 4, dim3(64, 4), 0, stream>>>(
          x, (const float*)d_in[base + 2], (const float*)d_in[base + 3],
          (const float*)d_in[base + 4], feat, el, er, n);
      scatter_pair<<<(eN[r] + 255) / 256, 256, 0, stream>>>(
          (const int*)d_in[base], (const int*)d_in[base + 1], el, er, off + (size_t)r * n,
          cur + (size_t)r * n, pairs, ebase, eN[r]);
      agg1<<<(n + 3) / 4, 256, 0, stream>>>(feat, off + (size_t)r * n, pairs, ebase, out, n);
      ebase += eN[r];
    }
  }
}

// Round 3
// 656.092 us; speedup vs baseline: 1.5145x; 1.2286x over previous
//
#include <hip/hip_runtime.h>

#define DIM 64
#define NEG 0.2f
#define SB 1024

// ================= fused projection: feat_r = x @ W_r ; el_r ; er_r (r=0,1,2) ==============
__global__ __launch_bounds__(256) void proj3(
    const float* __restrict__ x,
    const float* __restrict__ W0, const float* __restrict__ W1, const float* __restrict__ W2,
    const float* __restrict__ al0, const float* __restrict__ al1, const float* __restrict__ al2,
    const float* __restrict__ ar0, const float* __restrict__ ar1, const float* __restrict__ ar2,
    float* __restrict__ feat, float* __restrict__ el, float* __restrict__ er, int n) {
  __shared__ float Ws[3][DIM][DIM];  // 48 KB
  __shared__ float Xs[4][DIM];
  const int lane = threadIdx.x, ty = threadIdx.y;
  int tid = ty * 64 + lane;
  for (int i = tid; i < DIM * DIM; i += 256) {
    int k = i >> 6, c = i & 63;
    Ws[0][k][c] = W0[i];
    Ws[1][k][c] = W1[i];
    Ws[2][k][c] = W2[i];
  }
  int row = blockIdx.x * 4 + ty;
  int rowc = row < n ? row : n - 1;
  Xs[ty][lane] = x[(size_t)rowc * DIM + lane];  // read x ONCE for all 3 relations
  __syncthreads();
  if (row >= n) return;

  float a0 = 0.f, a1 = 0.f, a2 = 0.f;
#pragma unroll
  for (int k = 0; k < DIM; ++k) {
    float xv = Xs[ty][k];  // LDS broadcast (same addr across lanes)
    a0 = fmaf(xv, Ws[0][k][lane], a0);
    a1 = fmaf(xv, Ws[1][k][lane], a1);
    a2 = fmaf(xv, Ws[2][k][lane], a2);
  }
  feat[(size_t)row * DIM + lane] = a0;
  feat[((size_t)n + row) * DIM + lane] = a1;
  feat[((size_t)2 * n + row) * DIM + lane] = a2;

  float pl0 = a0 * al0[lane], pr0 = a0 * ar0[lane];
  float pl1 = a1 * al1[lane], pr1 = a1 * ar1[lane];
  float pl2 = a2 * al2[lane], pr2 = a2 * ar2[lane];
#pragma unroll
  for (int o = 32; o > 0; o >>= 1) {
    pl0 += __shfl_xor(pl0, o, 64); pr0 += __shfl_xor(pr0, o, 64);
    pl1 += __shfl_xor(pl1, o, 64); pr1 += __shfl_xor(pr1, o, 64);
    pl2 += __shfl_xor(pl2, o, 64); pr2 += __shfl_xor(pr2, o, 64);
  }
  if (lane == 0) {
    el[row] = pl0;         er[row] = pr0;
    el[n + row] = pl1;     er[n + row] = pr1;
    el[2 * n + row] = pl2; er[2 * n + row] = pr2;
  }
}

// ---------------- lean-path single-relation projection ----------------
__global__ __launch_bounds__(256) void proj_kernel(
    const float* __restrict__ x, const float* __restrict__ W,
    const float* __restrict__ al, const float* __restrict__ ar,
    float* __restrict__ feat, float* __restrict__ el, float* __restrict__ er, int n) {
  __shared__ float Ws[DIM][DIM];
  int tid = threadIdx.y * 64 + threadIdx.x;
  for (int i = tid; i < DIM * DIM; i += 256) Ws[i >> 6][i & 63] = W[i];
  __syncthreads();
  int row = blockIdx.x * 4 + threadIdx.y;
  if (row >= n) return;
  int lane = threadIdx.x;
  const float* xr = x + (size_t)row * DIM;
  float acc = 0.f;
#pragma unroll
  for (int k = 0; k < DIM; ++k) acc = fmaf(xr[k], Ws[k][lane], acc);
  feat[(size_t)row * DIM + lane] = acc;
  float pl = acc * al[lane], pr = acc * ar[lane];
#pragma unroll
  for (int o = 32; o > 0; o >>= 1) {
    pl += __shfl_xor(pl, o, 64);
    pr += __shfl_xor(pr, o, 64);
  }
  if (lane == 0) { el[row] = pl; er[row] = pr; }
}

__global__ void init_out(float* __restrict__ out,
                         const float* __restrict__ b0, const float* __restrict__ b1,
                         const float* __restrict__ b2, int n) {
  int i = blockIdx.x * blockDim.x + threadIdx.x;
  if (i < n * DIM) {
    int c = i & (DIM - 1);
    out[i] = b0[c] + b1[c] + b2[c];
  }
}

// ================= CSR build (all 3 relations in one concatenated histogram) ==============
__global__ void count3(const int* __restrict__ d0, const int* __restrict__ d1,
                       const int* __restrict__ d2, int e0, int e1, int e2,
                       int* __restrict__ cnt, int n) {
  int i = blockIdx.x * blockDim.x + threadIdx.x;
  int r, li;
  const int* dp;
  if (i < e0)            { r = 0; li = i;           dp = d0; }
  else if (i < e0 + e1)  { r = 1; li = i - e0;      dp = d1; }
  else if (i < e0 + e1 + e2) { r = 2; li = i - e0 - e1; dp = d2; }
  else return;
  atomicAdd(&cnt[r * n + dp[li]], 1);
}

__global__ __launch_bounds__(SB) void scan1(const int* __restrict__ cnt, int* __restrict__ off,
                                            int* __restrict__ bsum, int n) {
  __shared__ int sm[SB];
  int i = blockIdx.x * SB + threadIdx.x;
  int v = (i < n) ? cnt[i] : 0;
  sm[threadIdx.x] = v;
  __syncthreads();
  for (int o = 1; o < SB; o <<= 1) {
    int t = ((int)threadIdx.x >= o) ? sm[threadIdx.x - o] : 0;
    __syncthreads();
    sm[threadIdx.x] += t;
    __syncthreads();
  }
  if (i < n) off[i + 1] = sm[threadIdx.x];
  if (threadIdx.x == SB - 1) bsum[blockIdx.x] = sm[SB - 1];
}

__global__ __launch_bounds__(SB) void scan2(int* __restrict__ bsum, int nb) {
  __shared__ int sm[SB];
  int v = ((int)threadIdx.x < nb) ? bsum[threadIdx.x] : 0;
  sm[threadIdx.x] = v;
  __syncthreads();
  for (int o = 1; o < SB; o <<= 1) {
    int t = ((int)threadIdx.x >= o) ? sm[threadIdx.x - o] : 0;
    __syncthreads();
    sm[threadIdx.x] += t;
    __syncthreads();
  }
  if ((int)threadIdx.x < nb) bsum[threadIdx.x] = sm[threadIdx.x] - v;
}

__global__ __launch_bounds__(SB) void scan3(int* __restrict__ off, const int* __restrict__ bsum,
                                            int n) {
  int i = blockIdx.x * SB + threadIdx.x;
  if (i < n) off[i + 1] += bsum[blockIdx.x];
  if (i == 0) off[0] = 0;
}

// scatter (src, leaky(el[src]+er[dst])) pairs into the dst-CSR buckets, all 3 relations
__global__ void scatter3(const int* __restrict__ s0, const int* __restrict__ d0,
                         const int* __restrict__ s1, const int* __restrict__ d1,
                         const int* __restrict__ s2, const int* __restrict__ d2,
                         int e0, int e1, int e2,
                         const float* __restrict__ el, const float* __restrict__ er,
                         const int* __restrict__ off, int* __restrict__ cur,
                         int2* __restrict__ pairs, int n) {
  int i = blockIdx.x * blockDim.x + threadIdx.x;
  int r, li;
  const int *sp, *dp;
  if (i < e0)            { r = 0; li = i;           sp = s0; dp = d0; }
  else if (i < e0 + e1)  { r = 1; li = i - e0;      sp = s1; dp = d1; }
  else if (i < e0 + e1 + e2) { r = 2; li = i - e0 - e1; sp = s2; dp = d2; }
  else return;
  int sN = sp[li], d = dp[li];
  int gi = r * n + d;
  float v = el[r * n + sN] + er[gi];
  v = v > 0.f ? v : NEG * v;
  int p = atomicAdd(&cur[gi], 1);
  int2 pr;
  pr.x = sN;
  pr.y = __float_as_int(v);
  pairs[off[gi] + p] = pr;
}

__global__ void scatter_pair(const int* __restrict__ src, const int* __restrict__ dst,
                             const float* __restrict__ el, const float* __restrict__ er,
                             const int* __restrict__ off_r, int* __restrict__ cur_r,
                             int2* __restrict__ pairs, int ebase, int e) {
  int i = blockIdx.x * blockDim.x + threadIdx.x;
  if (i < e) {
    int d = dst[i], sN = src[i];
    float v = el[sN] + er[d];
    v = v > 0.f ? v : NEG * v;
    int p = atomicAdd(&cur_r[d], 1);
    int2 pr;
    pr.x = sN;
    pr.y = __float_as_int(v);
    pairs[off_r[d] + p - ebase] = pr;
  }
}

// ================= per-node softmax + aggregation: HALF-wave per node, float2/lane =========
// fast path deg<=32 (P[deg>32] ~ 1e-8 at Poisson(10)); unroll-4 gather loop for MLP
__device__ __forceinline__ float2 rel2(const float* __restrict__ feat,
                                       const int2* __restrict__ pairs,
                                       int beg, int end, int hl, int sl) {
  float2 acc = make_float2(0.f, 0.f);
  int deg = end - beg;
  if (deg <= 0) return acc;
  const int lbase = hl << 5;
  const int coff = sl << 1;
  float s;
  if (deg <= 32) {
    int2 pr = (sl < deg) ? pairs[beg + sl] : make_int2(0, 0xFF800000);  // pad = -inf
    float v = __int_as_float(pr.y);
    float m = v;
#pragma unroll
    for (int o = 16; o > 0; o >>= 1) m = fmaxf(m, __shfl_xor(m, o, 64));  // half-wave reduce
    float a = (sl < deg) ? __expf(v - m) : 0.f;
    float t = a;
#pragma unroll
    for (int o = 16; o > 0; o >>= 1) t += __shfl_xor(t, o, 64);
    s = t;
    int j = 0, bulk = deg & ~3;
    for (; j < bulk; j += 4) {  // 4 independent gathers in flight
      int sn0 = __shfl(pr.x, lbase + j, 64);     float a0 = __shfl(a, lbase + j, 64);
      int sn1 = __shfl(pr.x, lbase + j + 1, 64); float a1 = __shfl(a, lbase + j + 1, 64);
      int sn2 = __shfl(pr.x, lbase + j + 2, 64); float a2 = __shfl(a, lbase + j + 2, 64);
      int sn3 = __shfl(pr.x, lbase + j + 3, 64); float a3 = __shfl(a, lbase + j + 3, 64);
      float2 f0 = *(const float2*)(feat + ((size_t)sn0 << 6) + coff);
      float2 f1 = *(const float2*)(feat + ((size_t)sn1 << 6) + coff);
      float2 f2 = *(const float2*)(feat + ((size_t)sn2 << 6) + coff);
      float2 f3 = *(const float2*)(feat + ((size_t)sn3 << 6) + coff);
      acc.x = fmaf(a0, f0.x, acc.x); acc.y = fmaf(a0, f0.y, acc.y);
      acc.x = fmaf(a1, f1.x, acc.x); acc.y = fmaf(a1, f1.y, acc.y);
      acc.x = fmaf(a2, f2.x, acc.x); acc.y = fmaf(a2, f2.y, acc.y);
      acc.x = fmaf(a3, f3.x, acc.x); acc.y = fmaf(a3, f3.y, acc.y);
    }
    for (; j < deg; ++j) {
      int sn = __shfl(pr.x, lbase + j, 64);
      float aj = __shfl(a, lbase + j, 64);
      float2 f = *(const float2*)(feat + ((size_t)sn << 6) + coff);
      acc.x = fmaf(aj, f.x, acc.x);
      acc.y = fmaf(aj, f.y, acc.y);
    }
  } else {
    // rare chunked fallback
    float m = -3.4e38f;
    for (int i = beg + sl; i < end; i += 32) m = fmaxf(m, __int_as_float(pairs[i].y));
#pragma unroll
    for (int o = 16; o > 0; o >>= 1) m = fmaxf(m, __shfl_xor(m, o, 64));
    s = 0.f;
    for (int base = beg; base < end; base += 32) {
      int cm = min(32, end - base);
      int2 pr = (sl < cm) ? pairs[base + sl] : make_int2(0, 0);
      float a = (sl < cm) ? __expf(__int_as_float(pr.y) - m) : 0.f;
      float t = a;
#pragma unroll
      for (int o = 16; o > 0; o >>= 1) t += __shfl_xor(t, o, 64);
      s += t;
      for (int j = 0; j < cm; ++j) {
        int sn = __shfl(pr.x, lbase + j, 64);
        float aj = __shfl(a, lbase + j, 64);
        float2 f = *(const float2*)(feat + ((size_t)sn << 6) + coff);
        acc.x = fmaf(aj, f.x, acc.x);
        acc.y = fmaf(aj, f.y, acc.y);
      }
    }
  }
  acc.x /= s;
  acc.y /= s;
  return acc;
}

__global__ __launch_bounds__(256) void agg3(
    const float* __restrict__ feat, const int* __restrict__ off, const int2* __restrict__ pairs,
    const float* __restrict__ b0, const float* __restrict__ b1, const float* __restrict__ b2,
    float* __restrict__ out, int n) {
  int wave = (blockIdx.x * blockDim.x + threadIdx.x) >> 6;
  int lane = threadIdx.x & 63;
  int hl = lane >> 5, sl = lane & 31;
  int node = (wave << 1) + hl;
  if (node >= n) return;
  int c0 = sl << 1;
  float2 r;
  r.x = b0[c0] + b1[c0] + b2[c0];
  r.y = b0[c0 + 1] + b1[c0 + 1] + b2[c0 + 1];
  float2 c;
  c = rel2(feat, pairs, off[node], off[node + 1], hl, sl);
  r.x += c.x; r.y += c.y;
  c = rel2(feat + (size_t)n * DIM, pairs, off[n + node], off[n + node + 1], hl, sl);
  r.x += c.x; r.y += c.y;
  c = rel2(feat + (size_t)2 * n * DIM, pairs, off[2 * n + node], off[2 * n + node + 1], hl, sl);
  r.x += c.x; r.y += c.y;
  *(float2*)(out + ((size_t)node << 6) + c0) = r;
}

__global__ __launch_bounds__(256) void agg1(
    const float* __restrict__ feat, const int* __restrict__ off_r,
    const int2* __restrict__ pairs, int ebase, float* __restrict__ out, int n) {
  int wave = (blockIdx.x * blockDim.x + threadIdx.x) >> 6;
  int lane = threadIdx.x & 63;
  int hl = lane >> 5, sl = lane & 31;
  int node = (wave << 1) + hl;
  if (node >= n) return;
  float2 c = rel2(feat, pairs, off_r[node] - ebase, off_r[node + 1] - ebase, hl, sl);
  float* op = out + ((size_t)node << 6) + (sl << 1);
  op[0] += c.x;
  op[1] += c.y;
}

static inline char* alignup(char* p) {
  return (char*)(((uintptr_t)p + 255) & ~(uintptr_t)255);
}

extern "C" void kernel_launch(void* const* d_in, const int* in_sizes, int n_in,
                              void* d_out, int out_size, void* d_ws, size_t ws_size,
                              hipStream_t stream) {
  const float* x = (const float*)d_in[0];
  const int n = in_sizes[0] / DIM;
  const int m = 3 * n;
  float* out = (float*)d_out;

  const int eN[3] = {in_sizes[1], in_sizes[7], in_sizes[13]};
  const int eTot = eN[0] + eN[1] + eN[2];

  const size_t featB = (size_t)n * DIM * sizeof(float);
  const size_t nB = (size_t)n * sizeof(float);

  const size_t needFused = 3 * featB + 6 * nB + 2 * (size_t)m * 4 + (size_t)(m + 2) * 4 +
                           SB * 4 + (size_t)eTot * 8 + 16 * 256;
  const bool fused = ws_size >= needFused;

  char* w = (char*)d_ws;
  float* feat = (float*)w;  w += fused ? 3 * featB : featB;  w = alignup(w);
  float* el = (float*)w;    w += fused ? 3 * nB : nB;        w = alignup(w);
  float* er = (float*)w;    w += fused ? 3 * nB : nB;        w = alignup(w);
  int* cnt = (int*)w;       w += (size_t)m * 4;              // cnt+cur contiguous (one memset)
  int* cur = (int*)w;       w += (size_t)m * 4;              w = alignup(w);
  int* off = (int*)w;       w += (size_t)(m + 1) * 4;        w = alignup(w);
  int* bsum = (int*)w;      w += SB * 4;                     w = alignup(w);
  int2* pairs = (int2*)w;

  const int nb = (m + SB - 1) / SB;  // 293 for n=100000 (scan2 handles nb<=1024)

  hipMemsetAsync(cnt, 0, (size_t)2 * m * sizeof(int), stream);
  count3<<<(eTot + 255) / 256, 256, 0, stream>>>(
      (const int*)d_in[2], (const int*)d_in[8], (const int*)d_in[14],
      eN[0], eN[1], eN[2], cnt, n);
  scan1<<<nb, SB, 0, stream>>>(cnt, off, bsum, m);
  scan2<<<1, SB, 0, stream>>>(bsum, nb);
  scan3<<<nb, SB, 0, stream>>>(off, bsum, m);

  if (fused) {
    proj3<<<(n + 3) / 4, dim3(64, 4), 0, stream>>>(
        x, (const float*)d_in[3], (const float*)d_in[9], (const float*)d_in[15],
        (const float*)d_in[4], (const float*)d_in[10], (const float*)d_in[16],
        (const float*)d_in[5], (const float*)d_in[11], (const float*)d_in[17],
        feat, el, er, n);
    scatter3<<<(eTot + 255) / 256, 256, 0, stream>>>(
        (const int*)d_in[1], (const int*)d_in[2], (const int*)d_in[7], (const int*)d_in[8],
        (const int*)d_in[13], (const int*)d_in[14], eN[0], eN[1], eN[2],
        el, er, off, cur, pairs, n);
    agg3<<<(n + 7) / 8, 256, 0, stream>>>(
        feat, off, pairs,
        (const float*)d_in[6], (const float*)d_in[12], (const float*)d_in[18], out, n);
  } else {
    init_out<<<(n * DIM + 255) / 256, 256, 0, stream>>>(
        out, (const float*)d_in[6], (const float*)d_in[12], (const float*)d_in[18], n);
    int ebase = 0;
    for (int r = 0; r < 3; ++r) {
      const int base = 1 + r * 6;
      proj_kernel<<<(n + 3) / 4, dim3(64, 4), 0, stream>>>(
          x, (const float*)d_in[base + 2], (const float*)d_in[base + 3],
          (const float*)d_in[base + 4], feat, el, er, n);
      scatter_pair<<<(eN[r] + 255) / 256, 256, 0, stream>>>(
          (const int*)d_in[base], (const int*)d_in[base + 1], el, er, off + (size_t)r * n,
          cur + (size_t)r * n, pairs, ebase, eN[r]);
      agg1<<<(n + 7) / 8, 256, 0, stream>>>(feat, off + (size_t)r * n, pairs, ebase, out, n);
      ebase += eN[r];
    }
  }
}

// Round 5
// 562.691 us; speedup vs baseline: 1.7659x; 1.1660x over previous
//
#include <hip/hip_runtime.h>

#define DIM 64
#define NEG 0.2f
#define SB 1024
#define RPW 8  // rows per wave in proj3

__device__ __forceinline__ float rl(float v, int l) {
  return __int_as_float(__builtin_amdgcn_readlane(__float_as_int(v), l));
}

// ================= prep: q[b] = W_rel @ (al|ar)  [row-dot!], bias = b0+b1+b2 =================
// grid 7 blocks x 64 threads: b=0..5 -> (rel=b>>1, side=b&1); b=6 -> bias sum
// el[i] = sum_c feat[i,c]*al[c] = x[i,:] . q  with q[k] = sum_c W[k,c]*al[c]  (W row k . al)
__global__ __launch_bounds__(64) void prep_kernel(
    const float* __restrict__ W0, const float* __restrict__ W1, const float* __restrict__ W2,
    const float* __restrict__ al0, const float* __restrict__ ar0,
    const float* __restrict__ al1, const float* __restrict__ ar1,
    const float* __restrict__ al2, const float* __restrict__ ar2,
    const float* __restrict__ b0, const float* __restrict__ b1, const float* __restrict__ b2,
    float* __restrict__ q, float* __restrict__ bias) {
  int b = blockIdx.x, c = threadIdx.x;
  if (b < 6) {
    int rel = b >> 1;
    const float* W = rel == 0 ? W0 : (rel == 1 ? W1 : W2);
    const float* a;
    if (b & 1) a = rel == 0 ? ar0 : (rel == 1 ? ar1 : ar2);
    else       a = rel == 0 ? al0 : (rel == 1 ? al1 : al2);
    float s = 0.f;
#pragma unroll
    for (int j = 0; j < DIM; ++j) s = fmaf(W[c * DIM + j], a[j], s);  // thread c: W row c . a
    q[b * DIM + c] = s;
  } else {
    bias[c] = b0[c] + b1[c] + b2[c];
  }
}

// ================= el/er for all 3 relations: one thread per row, zero cross-lane =========
__global__ __launch_bounds__(256) void elr_kernel(
    const float* __restrict__ x, const float* __restrict__ q,
    float* __restrict__ el, float* __restrict__ er, int n) {
  __shared__ float Qs[6 * DIM];
  for (int i = threadIdx.x; i < 6 * DIM; i += 256) Qs[i] = q[i];
  __syncthreads();
  int i = blockIdx.x * blockDim.x + threadIdx.x;
  if (i >= n) return;
  const float4* x4 = (const float4*)x;
  const float4* Q4 = (const float4*)Qs;
  float a[6] = {0.f, 0.f, 0.f, 0.f, 0.f, 0.f};
#pragma unroll 4
  for (int t = 0; t < 16; ++t) {
    float4 xv = x4[(size_t)i * 16 + t];
#pragma unroll
    for (int j = 0; j < 6; ++j) {
      float4 qv = Q4[j * 16 + t];  // same addr across lanes: LDS broadcast
      a[j] = fmaf(xv.x, qv.x, a[j]);
      a[j] = fmaf(xv.y, qv.y, a[j]);
      a[j] = fmaf(xv.z, qv.z, a[j]);
      a[j] = fmaf(xv.w, qv.w, a[j]);
    }
  }
#pragma unroll
  for (int r = 0; r < 3; ++r) {
    el[(size_t)r * n + i] = a[2 * r];
    er[(size_t)r * n + i] = a[2 * r + 1];
  }
}

// ================= proj3: pure GEMM, 8 rows/wave, readlane x-broadcast ====================
__global__ __launch_bounds__(256) void proj3(
    const float* __restrict__ x,
    const float* __restrict__ W0, const float* __restrict__ W1, const float* __restrict__ W2,
    float* __restrict__ feat, int n) {
  __shared__ float WsP[3 * 4096];  // [rel][k2:32][lane:64][2] k-pair packed (48 KB)
  const int lane = threadIdx.x & 63;
  const int wv = threadIdx.x >> 6;
  for (int i = threadIdx.x; i < DIM * DIM; i += 256) {
    int k = i >> 6, c = i & 63;
    int d = (k >> 1) * 128 + c * 2 + (k & 1);
    WsP[d] = W0[i];
    WsP[4096 + d] = W1[i];
    WsP[8192 + d] = W2[i];
  }
  __syncthreads();

  const int rowbase = (blockIdx.x * 4 + wv) * RPW;
  float xr[RPW];
#pragma unroll
  for (int r = 0; r < RPW; ++r) {
    int row = rowbase + r;
    row = row < n ? row : n - 1;
    xr[r] = x[(size_t)row * DIM + lane];
  }
  float a0[RPW], a1[RPW], a2[RPW];
#pragma unroll
  for (int r = 0; r < RPW; ++r) { a0[r] = 0.f; a1[r] = 0.f; a2[r] = 0.f; }

  const float2* Wp0 = (const float2*)WsP;
  const float2* Wp1 = (const float2*)(WsP + 4096);
  const float2* Wp2 = (const float2*)(WsP + 8192);
#pragma unroll 8
  for (int k2 = 0; k2 < 32; ++k2) {
    float2 w0 = Wp0[k2 * 64 + lane];  // conflict-free: lanes stride 8B
    float2 w1 = Wp1[k2 * 64 + lane];
    float2 w2 = Wp2[k2 * 64 + lane];
#pragma unroll
    for (int r = 0; r < RPW; ++r) {
      float xv0 = rl(xr[r], 2 * k2);      // x broadcast via readlane: no LDS pipe
      float xv1 = rl(xr[r], 2 * k2 + 1);
      a0[r] = fmaf(xv1, w0.y, fmaf(xv0, w0.x, a0[r]));
      a1[r] = fmaf(xv1, w1.y, fmaf(xv0, w1.x, a1[r]));
      a2[r] = fmaf(xv1, w2.y, fmaf(xv0, w2.x, a2[r]));
    }
  }
#pragma unroll
  for (int r = 0; r < RPW; ++r) {
    int row = rowbase + r;
    if (row < n) {
      feat[(size_t)row * DIM + lane] = a0[r];
      feat[((size_t)n + row) * DIM + lane] = a1[r];
      feat[((size_t)2 * n + row) * DIM + lane] = a2[r];
    }
  }
}

// ---------------- lean-path kernels (fallback if ws too small) ----------------
__global__ __launch_bounds__(256) void proj_kernel(
    const float* __restrict__ x, const float* __restrict__ W,
    const float* __restrict__ al, const float* __restrict__ ar,
    float* __restrict__ feat, float* __restrict__ el, float* __restrict__ er, int n) {
  __shared__ float Ws[DIM][DIM];
  int tid = threadIdx.y * 64 + threadIdx.x;
  for (int i = tid; i < DIM * DIM; i += 256) Ws[i >> 6][i & 63] = W[i];
  __syncthreads();
  int row = blockIdx.x * 4 + threadIdx.y;
  if (row >= n) return;
  int lane = threadIdx.x;
  const float* xr = x + (size_t)row * DIM;
  float acc = 0.f;
#pragma unroll
  for (int k = 0; k < DIM; ++k) acc = fmaf(xr[k], Ws[k][lane], acc);
  feat[(size_t)row * DIM + lane] = acc;
  float pl = acc * al[lane], pr = acc * ar[lane];
#pragma unroll
  for (int o = 32; o > 0; o >>= 1) {
    pl += __shfl_xor(pl, o, 64);
    pr += __shfl_xor(pr, o, 64);
  }
  if (lane == 0) { el[row] = pl; er[row] = pr; }
}

__global__ void init_out(float* __restrict__ out,
                         const float* __restrict__ b0, const float* __restrict__ b1,
                         const float* __restrict__ b2, int n) {
  int i = blockIdx.x * blockDim.x + threadIdx.x;
  if (i < n * DIM) {
    int c = i & (DIM - 1);
    out[i] = b0[c] + b1[c] + b2[c];
  }
}

// ================= CSR build ==============
__global__ void count3(const int* __restrict__ d0, const int* __restrict__ d1,
                       const int* __restrict__ d2, int e0, int e1, int e2,
                       int* __restrict__ cnt, int n) {
  int i = blockIdx.x * blockDim.x + threadIdx.x;
  int r, li;
  const int* dp;
  if (i < e0)                { r = 0; li = i;           dp = d0; }
  else if (i < e0 + e1)      { r = 1; li = i - e0;      dp = d1; }
  else if (i < e0 + e1 + e2) { r = 2; li = i - e0 - e1; dp = d2; }
  else return;
  atomicAdd(&cnt[r * n + dp[li]], 1);
}

__global__ __launch_bounds__(SB) void scan1(const int* __restrict__ cnt, int* __restrict__ off,
                                            int* __restrict__ bsum, int n) {
  __shared__ int sm[SB];
  int i = blockIdx.x * SB + threadIdx.x;
  int v = (i < n) ? cnt[i] : 0;
  sm[threadIdx.x] = v;
  __syncthreads();
  for (int o = 1; o < SB; o <<= 1) {
    int t = ((int)threadIdx.x >= o) ? sm[threadIdx.x - o] : 0;
    __syncthreads();
    sm[threadIdx.x] += t;
    __syncthreads();
  }
  if (i < n) off[i + 1] = sm[threadIdx.x];
  if (threadIdx.x == SB - 1) bsum[blockIdx.x] = sm[SB - 1];
}

__global__ __launch_bounds__(SB) void scan2(int* __restrict__ bsum, int nb) {
  __shared__ int sm[SB];
  int v = ((int)threadIdx.x < nb) ? bsum[threadIdx.x] : 0;
  sm[threadIdx.x] = v;
  __syncthreads();
  for (int o = 1; o < SB; o <<= 1) {
    int t = ((int)threadIdx.x >= o) ? sm[threadIdx.x - o] : 0;
    __syncthreads();
    sm[threadIdx.x] += t;
    __syncthreads();
  }
  if ((int)threadIdx.x < nb) bsum[threadIdx.x] = sm[threadIdx.x] - v;
}

__global__ __launch_bounds__(SB) void scan3(int* __restrict__ off, const int* __restrict__ bsum,
                                            int n) {
  int i = blockIdx.x * SB + threadIdx.x;
  if (i < n) off[i + 1] += bsum[blockIdx.x];
  if (i == 0) off[0] = 0;
}

__global__ void scatter3(const int* __restrict__ s0, const int* __restrict__ d0,
                         const int* __restrict__ s1, const int* __restrict__ d1,
                         const int* __restrict__ s2, const int* __restrict__ d2,
                         int e0, int e1, int e2,
                         const float* __restrict__ el, const float* __restrict__ er,
                         const int* __restrict__ off, int* __restrict__ cur,
                         int2* __restrict__ pairs, int n) {
  int i = blockIdx.x * blockDim.x + threadIdx.x;
  int r, li;
  const int *sp, *dp;
  if (i < e0)                { r = 0; li = i;           sp = s0; dp = d0; }
  else if (i < e0 + e1)      { r = 1; li = i - e0;      sp = s1; dp = d1; }
  else if (i < e0 + e1 + e2) { r = 2; li = i - e0 - e1; sp = s2; dp = d2; }
  else return;
  int sN = sp[li], d = dp[li];
  int gi = r * n + d;
  float v = el[(size_t)r * n + sN] + er[gi];
  v = v > 0.f ? v : NEG * v;
  int p = atomicAdd(&cur[gi], 1);
  int2 pr;
  pr.x = sN;
  pr.y = __float_as_int(v);
  pairs[off[gi] + p] = pr;
}

__global__ void scatter_pair(const int* __restrict__ src, const int* __restrict__ dst,
                             const float* __restrict__ el, const float* __restrict__ er,
                             const int* __restrict__ off_r, int* __restrict__ cur_r,
                             int2* __restrict__ pairs, int ebase, int e) {
  int i = blockIdx.x * blockDim.x + threadIdx.x;
  if (i < e) {
    int d = dst[i], sN = src[i];
    float v = el[sN] + er[d];
    v = v > 0.f ? v : NEG * v;
    int p = atomicAdd(&cur_r[d], 1);
    int2 pr;
    pr.x = sN;
    pr.y = __float_as_int(v);
    pairs[off_r[d] + p - ebase] = pr;
  }
}

// ================= per-node softmax + aggregation: half-wave per node, float2/lane =========
__device__ __forceinline__ float2 rel2(const float* __restrict__ feat,
                                       const int2* __restrict__ pairs,
                                       int beg, int end, int hl, int sl) {
  float2 acc = make_float2(0.f, 0.f);
  int deg = end - beg;
  if (deg <= 0) return acc;
  const int lbase = hl << 5;
  const int coff = sl << 1;
  float s;
  if (deg <= 32) {
    int2 pr = (sl < deg) ? pairs[beg + sl] : make_int2(0, 0xFF800000);  // pad = -inf
    float v = __int_as_float(pr.y);
    float m = v;
#pragma unroll
    for (int o = 16; o > 0; o >>= 1) m = fmaxf(m, __shfl_xor(m, o, 64));
    float a = (sl < deg) ? __expf(v - m) : 0.f;
    float t = a;
#pragma unroll
    for (int o = 16; o > 0; o >>= 1) t += __shfl_xor(t, o, 64);
    s = t;
    int j = 0, bulk = deg & ~3;
    for (; j < bulk; j += 4) {  // 4 independent gathers in flight
      int sn0 = __shfl(pr.x, lbase + j, 64);     float a0 = __shfl(a, lbase + j, 64);
      int sn1 = __shfl(pr.x, lbase + j + 1, 64); float a1 = __shfl(a, lbase + j + 1, 64);
      int sn2 = __shfl(pr.x, lbase + j + 2, 64); float a2 = __shfl(a, lbase + j + 2, 64);
      int sn3 = __shfl(pr.x, lbase + j + 3, 64); float a3 = __shfl(a, lbase + j + 3, 64);
      float2 f0 = *(const float2*)(feat + ((size_t)sn0 << 6) + coff);
      float2 f1 = *(const float2*)(feat + ((size_t)sn1 << 6) + coff);
      float2 f2 = *(const float2*)(feat + ((size_t)sn2 << 6) + coff);
      float2 f3 = *(const float2*)(feat + ((size_t)sn3 << 6) + coff);
      acc.x = fmaf(a0, f0.x, acc.x); acc.y = fmaf(a0, f0.y, acc.y);
      acc.x = fmaf(a1, f1.x, acc.x); acc.y = fmaf(a1, f1.y, acc.y);
      acc.x = fmaf(a2, f2.x, acc.x); acc.y = fmaf(a2, f2.y, acc.y);
      acc.x = fmaf(a3, f3.x, acc.x); acc.y = fmaf(a3, f3.y, acc.y);
    }
    for (; j < deg; ++j) {
      int sn = __shfl(pr.x, lbase + j, 64);
      float aj = __shfl(a, lbase + j, 64);
      float2 f = *(const float2*)(feat + ((size_t)sn << 6) + coff);
      acc.x = fmaf(aj, f.x, acc.x);
      acc.y = fmaf(aj, f.y, acc.y);
    }
  } else {
    float m = -3.4e38f;
    for (int i = beg + sl; i < end; i += 32) m = fmaxf(m, __int_as_float(pairs[i].y));
#pragma unroll
    for (int o = 16; o > 0; o >>= 1) m = fmaxf(m, __shfl_xor(m, o, 64));
    s = 0.f;
    for (int base = beg; base < end; base += 32) {
      int cm = min(32, end - base);
      int2 pr = (sl < cm) ? pairs[base + sl] : make_int2(0, 0);
      float a = (sl < cm) ? __expf(__int_as_float(pr.y) - m) : 0.f;
      float t = a;
#pragma unroll
      for (int o = 16; o > 0; o >>= 1) t += __shfl_xor(t, o, 64);
      s += t;
      for (int j = 0; j < cm; ++j) {
        int sn = __shfl(pr.x, lbase + j, 64);
        float aj = __shfl(a, lbase + j, 64);
        float2 f = *(const float2*)(feat + ((size_t)sn << 6) + coff);
        acc.x = fmaf(aj, f.x, acc.x);
        acc.y = fmaf(aj, f.y, acc.y);
      }
    }
  }
  acc.x /= s;
  acc.y /= s;
  return acc;
}

__global__ __launch_bounds__(256) void agg3(
    const float* __restrict__ feat, const int* __restrict__ off, const int2* __restrict__ pairs,
    const float* __restrict__ bias, float* __restrict__ out, int n) {
  int wave = (blockIdx.x * blockDim.x + threadIdx.x) >> 6;
  int lane = threadIdx.x & 63;
  int hl = lane >> 5, sl = lane & 31;
  int node = (wave << 1) + hl;
  if (node >= n) return;
  // prefetch all 6 CSR bounds (independent loads)
  int o0b = off[node],         o0e = off[node + 1];
  int o1b = off[n + node],     o1e = off[n + node + 1];
  int o2b = off[2 * n + node], o2e = off[2 * n + node + 1];
  int c0 = sl << 1;
  float2 r = *(const float2*)(bias + c0);
  float2 c;
  c = rel2(feat, pairs, o0b, o0e, hl, sl);
  r.x += c.x; r.y += c.y;
  c = rel2(feat + (size_t)n * DIM, pairs, o1b, o1e, hl, sl);
  r.x += c.x; r.y += c.y;
  c = rel2(feat + (size_t)2 * n * DIM, pairs, o2b, o2e, hl, sl);
  r.x += c.x; r.y += c.y;
  *(float2*)(out + ((size_t)node << 6) + c0) = r;
}

__global__ __launch_bounds__(256) void agg1(
    const float* __restrict__ feat, const int* __restrict__ off_r,
    const int2* __restrict__ pairs, int ebase, float* __restrict__ out, int n) {
  int wave = (blockIdx.x * blockDim.x + threadIdx.x) >> 6;
  int lane = threadIdx.x & 63;
  int hl = lane >> 5, sl = lane & 31;
  int node = (wave << 1) + hl;
  if (node >= n) return;
  float2 c = rel2(feat, pairs, off_r[node] - ebase, off_r[node + 1] - ebase, hl, sl);
  float* op = out + ((size_t)node << 6) + (sl << 1);
  op[0] += c.x;
  op[1] += c.y;
}

static inline char* alignup(char* p) {
  return (char*)(((uintptr_t)p + 255) & ~(uintptr_t)255);
}

extern "C" void kernel_launch(void* const* d_in, const int* in_sizes, int n_in,
                              void* d_out, int out_size, void* d_ws, size_t ws_size,
                              hipStream_t stream) {
  const float* x = (const float*)d_in[0];
  const int n = in_sizes[0] / DIM;
  const int m = 3 * n;
  float* out = (float*)d_out;

  const int eN[3] = {in_sizes[1], in_sizes[7], in_sizes[13]};
  const int eTot = eN[0] + eN[1] + eN[2];

  const size_t featB = (size_t)n * DIM * sizeof(float);
  const size_t nB = (size_t)n * sizeof(float);

  const size_t needFused = 3 * featB + 6 * nB + 2 * (size_t)m * 4 + (size_t)(m + 2) * 4 +
                           SB * 4 + 448 * 4 + (size_t)eTot * 8 + 32 * 256;
  const bool fused = ws_size >= needFused;

  char* w = (char*)d_ws;
  float* feat = (float*)w;  w += fused ? 3 * featB : featB;  w = alignup(w);
  float* el = (float*)w;    w += fused ? 3 * nB : nB;        w = alignup(w);
  float* er = (float*)w;    w += fused ? 3 * nB : nB;        w = alignup(w);
  int* cnt = (int*)w;       w += (size_t)m * 4;              // cnt+cur contiguous (one memset)
  int* cur = (int*)w;       w += (size_t)m * 4;              w = alignup(w);
  int* off = (int*)w;       w += (size_t)(m + 1) * 4;        w = alignup(w);
  int* bsum = (int*)w;      w += SB * 4;                     w = alignup(w);
  float* qbuf = (float*)w;  w += 384 * 4;                    // 6 x 64 q-vectors
  float* bias = (float*)w;  w += 64 * 4;                     w = alignup(w);
  int2* pairs = (int2*)w;

  const int nb = (m + SB - 1) / SB;  // 293 for n=100000 (scan2 handles nb<=1024)

  hipMemsetAsync(cnt, 0, (size_t)2 * m * sizeof(int), stream);
  count3<<<(eTot + 255) / 256, 256, 0, stream>>>(
      (const int*)d_in[2], (const int*)d_in[8], (const int*)d_in[14],
      eN[0], eN[1], eN[2], cnt, n);
  scan1<<<nb, SB, 0, stream>>>(cnt, off, bsum, m);
  scan2<<<1, SB, 0, stream>>>(bsum, nb);
  scan3<<<nb, SB, 0, stream>>>(off, bsum, m);

  if (fused) {
    prep_kernel<<<7, 64, 0, stream>>>(
        (const float*)d_in[3], (const float*)d_in[9], (const float*)d_in[15],
        (const float*)d_in[4], (const float*)d_in[5],
        (const float*)d_in[10], (const float*)d_in[11],
        (const float*)d_in[16], (const float*)d_in[17],
        (const float*)d_in[6], (const float*)d_in[12], (const float*)d_in[18],
        qbuf, bias);
    elr_kernel<<<(n + 255) / 256, 256, 0, stream>>>(x, qbuf, el, er, n);
    proj3<<<(n + 4 * RPW - 1) / (4 * RPW), 256, 0, stream>>>(
        x, (const float*)d_in[3], (const float*)d_in[9], (const float*)d_in[15], feat, n);
    scatter3<<<(eTot + 255) / 256, 256, 0, stream>>>(
        (const int*)d_in[1], (const int*)d_in[2], (const int*)d_in[7], (const int*)d_in[8],
        (const int*)d_in[13], (const int*)d_in[14], eN[0], eN[1], eN[2],
        el, er, off, cur, pairs, n);
    agg3<<<(n + 7) / 8, 256, 0, stream>>>(feat, off, pairs, bias, out, n);
  } else {
    init_out<<<(n * DIM + 255) / 256, 256, 0, stream>>>(
        out, (const float*)d_in[6], (const float*)d_in[12], (const float*)d_in[18], n);
    int ebase = 0;
    for (int r = 0; r < 3; ++r) {
      const int base = 1 + r * 6;
      proj_kernel<<<(n + 3) / 4, dim3(64, 4), 0, stream>>>(
          x, (const float*)d_in[base + 2], (const float*)d_in[base + 3],
          (const float*)d_in[base + 4], feat, el, er, n);
      scatter_pair<<<(eN[r] + 255) / 256, 256, 0, stream>>>(
          (const int*)d_in[base], (const int*)d_in[base + 1], el, er, off + (size_t)r * n,
          cur + (size_t)r * n, pairs, ebase, eN[r]);
      agg1<<<(n + 7) / 8, 256, 0, stream>>>(feat, off + (size_t)r * n, pairs, ebase, out, n);
      ebase += eN[r];
    }
  }
}

// Round 6
// 558.820 us; speedup vs baseline: 1.7782x; 1.0069x over previous
//
#include <hip/hip_runtime.h>

#define DIM 64
#define NEG 0.2f
#define SB 1024
#define RPW 8   // rows per wave in proj3
#define NS 8    // dst-slices == XCD count; slice = blockIdx&7 -> XCD-affine writes

__device__ __forceinline__ float rl(float v, int l) {
  return __int_as_float(__builtin_amdgcn_readlane(__float_as_int(v), l));
}

// ================= prep: q[b] = W_rel @ (al|ar)  [row-dot], bias = b0+b1+b2 =================
__global__ __launch_bounds__(64) void prep_kernel(
    const float* __restrict__ W0, const float* __restrict__ W1, const float* __restrict__ W2,
    const float* __restrict__ al0, const float* __restrict__ ar0,
    const float* __restrict__ al1, const float* __restrict__ ar1,
    const float* __restrict__ al2, const float* __restrict__ ar2,
    const float* __restrict__ b0, const float* __restrict__ b1, const float* __restrict__ b2,
    float* __restrict__ q, float* __restrict__ bias) {
  int b = blockIdx.x, c = threadIdx.x;
  if (b < 6) {
    int rel = b >> 1;
    const float* W = rel == 0 ? W0 : (rel == 1 ? W1 : W2);
    const float* a;
    if (b & 1) a = rel == 0 ? ar0 : (rel == 1 ? ar1 : ar2);
    else       a = rel == 0 ? al0 : (rel == 1 ? al1 : al2);
    float s = 0.f;
#pragma unroll
    for (int j = 0; j < DIM; ++j) s = fmaf(W[c * DIM + j], a[j], s);  // thread c: W row c . a
    q[b * DIM + c] = s;
  } else {
    bias[c] = b0[c] + b1[c] + b2[c];
  }
}

// ================= el/er for all 3 relations: one thread per row =========
__global__ __launch_bounds__(256) void elr_kernel(
    const float* __restrict__ x, const float* __restrict__ q,
    float* __restrict__ el, float* __restrict__ er, int n) {
  __shared__ float Qs[6 * DIM];
  for (int i = threadIdx.x; i < 6 * DIM; i += 256) Qs[i] = q[i];
  __syncthreads();
  int i = blockIdx.x * blockDim.x + threadIdx.x;
  if (i >= n) return;
  const float4* x4 = (const float4*)x;
  const float4* Q4 = (const float4*)Qs;
  float a[6] = {0.f, 0.f, 0.f, 0.f, 0.f, 0.f};
#pragma unroll 4
  for (int t = 0; t < 16; ++t) {
    float4 xv = x4[(size_t)i * 16 + t];
#pragma unroll
    for (int j = 0; j < 6; ++j) {
      float4 qv = Q4[j * 16 + t];
      a[j] = fmaf(xv.x, qv.x, a[j]);
      a[j] = fmaf(xv.y, qv.y, a[j]);
      a[j] = fmaf(xv.z, qv.z, a[j]);
      a[j] = fmaf(xv.w, qv.w, a[j]);
    }
  }
#pragma unroll
  for (int r = 0; r < 3; ++r) {
    el[(size_t)r * n + i] = a[2 * r];
    er[(size_t)r * n + i] = a[2 * r + 1];
  }
}

// ================= proj3: 8 rows/wave, readlane x-broadcast ====================
__global__ __launch_bounds__(256) void proj3(
    const float* __restrict__ x,
    const float* __restrict__ W0, const float* __restrict__ W1, const float* __restrict__ W2,
    float* __restrict__ feat, int n) {
  __shared__ float WsP[3 * 4096];  // [rel][k2:32][lane:64][2] k-pair packed (48 KB)
  const int lane = threadIdx.x & 63;
  const int wv = threadIdx.x >> 6;
  for (int i = threadIdx.x; i < DIM * DIM; i += 256) {
    int k = i >> 6, c = i & 63;
    int d = (k >> 1) * 128 + c * 2 + (k & 1);
    WsP[d] = W0[i];
    WsP[4096 + d] = W1[i];
    WsP[8192 + d] = W2[i];
  }
  __syncthreads();

  const int rowbase = (blockIdx.x * 4 + wv) * RPW;
  float xr[RPW];
#pragma unroll
  for (int r = 0; r < RPW; ++r) {
    int row = rowbase + r;
    row = row < n ? row : n - 1;
    xr[r] = x[(size_t)row * DIM + lane];
  }
  float a0[RPW], a1[RPW], a2[RPW];
#pragma unroll
  for (int r = 0; r < RPW; ++r) { a0[r] = 0.f; a1[r] = 0.f; a2[r] = 0.f; }

  const float2* Wp0 = (const float2*)WsP;
  const float2* Wp1 = (const float2*)(WsP + 4096);
  const float2* Wp2 = (const float2*)(WsP + 8192);
#pragma unroll 8
  for (int k2 = 0; k2 < 32; ++k2) {
    float2 w0 = Wp0[k2 * 64 + lane];
    float2 w1 = Wp1[k2 * 64 + lane];
    float2 w2 = Wp2[k2 * 64 + lane];
#pragma unroll
    for (int r = 0; r < RPW; ++r) {
      float xv0 = rl(xr[r], 2 * k2);
      float xv1 = rl(xr[r], 2 * k2 + 1);
      a0[r] = fmaf(xv1, w0.y, fmaf(xv0, w0.x, a0[r]));
      a1[r] = fmaf(xv1, w1.y, fmaf(xv0, w1.x, a1[r]));
      a2[r] = fmaf(xv1, w2.y, fmaf(xv0, w2.x, a2[r]));
    }
  }
#pragma unroll
  for (int r = 0; r < RPW; ++r) {
    int row = rowbase + r;
    if (row < n) {
      feat[(size_t)row * DIM + lane] = a0[r];
      feat[((size_t)n + row) * DIM + lane] = a1[r];
      feat[((size_t)2 * n + row) * DIM + lane] = a2[r];
    }
  }
}

// ---------------- lean-path kernels (fallback if ws too small) ----------------
__global__ __launch_bounds__(256) void proj_kernel(
    const float* __restrict__ x, const float* __restrict__ W,
    const float* __restrict__ al, const float* __restrict__ ar,
    float* __restrict__ feat, float* __restrict__ el, float* __restrict__ er, int n) {
  __shared__ float Ws[DIM][DIM];
  int tid = threadIdx.y * 64 + threadIdx.x;
  for (int i = tid; i < DIM * DIM; i += 256) Ws[i >> 6][i & 63] = W[i];
  __syncthreads();
  int row = blockIdx.x * 4 + threadIdx.y;
  if (row >= n) return;
  int lane = threadIdx.x;
  const float* xr = x + (size_t)row * DIM;
  float acc = 0.f;
#pragma unroll
  for (int k = 0; k < DIM; ++k) acc = fmaf(xr[k], Ws[k][lane], acc);
  feat[(size_t)row * DIM + lane] = acc;
  float pl = acc * al[lane], pr = acc * ar[lane];
#pragma unroll
  for (int o = 32; o > 0; o >>= 1) {
    pl += __shfl_xor(pl, o, 64);
    pr += __shfl_xor(pr, o, 64);
  }
  if (lane == 0) { el[row] = pl; er[row] = pr; }
}

__global__ void init_out(float* __restrict__ out,
                         const float* __restrict__ b0, const float* __restrict__ b1,
                         const float* __restrict__ b2, int n) {
  int i = blockIdx.x * blockDim.x + threadIdx.x;
  if (i < n * DIM) {
    int c = i & (DIM - 1);
    out[i] = b0[c] + b1[c] + b2[c];
  }
}

// ================= CSR build ==============
__global__ void count3(const int* __restrict__ d0, const int* __restrict__ d1,
                       const int* __restrict__ d2, int e0, int e1, int e2,
                       int* __restrict__ cnt, int n) {
  int i = blockIdx.x * blockDim.x + threadIdx.x;
  int r, li;
  const int* dp;
  if (i < e0)                { r = 0; li = i;           dp = d0; }
  else if (i < e0 + e1)      { r = 1; li = i - e0;      dp = d1; }
  else if (i < e0 + e1 + e2) { r = 2; li = i - e0 - e1; dp = d2; }
  else return;
  atomicAdd(&cnt[r * n + dp[li]], 1);
}

__global__ __launch_bounds__(SB) void scan1(const int* __restrict__ cnt, int* __restrict__ off,
                                            int* __restrict__ bsum, int n) {
  __shared__ int sm[SB];
  int i = blockIdx.x * SB + threadIdx.x;
  int v = (i < n) ? cnt[i] : 0;
  sm[threadIdx.x] = v;
  __syncthreads();
  for (int o = 1; o < SB; o <<= 1) {
    int t = ((int)threadIdx.x >= o) ? sm[threadIdx.x - o] : 0;
    __syncthreads();
    sm[threadIdx.x] += t;
    __syncthreads();
  }
  if (i < n) off[i + 1] = sm[threadIdx.x];
  if (threadIdx.x == SB - 1) bsum[blockIdx.x] = sm[SB - 1];
}

__global__ __launch_bounds__(SB) void scan2(int* __restrict__ bsum, int nb) {
  __shared__ int sm[SB];
  int v = ((int)threadIdx.x < nb) ? bsum[threadIdx.x] : 0;
  sm[threadIdx.x] = v;
  __syncthreads();
  for (int o = 1; o < SB; o <<= 1) {
    int t = ((int)threadIdx.x >= o) ? sm[threadIdx.x - o] : 0;
    __syncthreads();
    sm[threadIdx.x] += t;
    __syncthreads();
  }
  if ((int)threadIdx.x < nb) bsum[threadIdx.x] = sm[threadIdx.x] - v;
}

__global__ __launch_bounds__(SB) void scan3(int* __restrict__ off, const int* __restrict__ bsum,
                                            int n) {
  int i = blockIdx.x * SB + threadIdx.x;
  if (i < n) off[i + 1] += bsum[blockIdx.x];
  if (i == 0) off[0] = 0;
}

// ======= dst-sliced XCD-affine scatter: block b -> chunk b>>3, slice b&7 =======
// All blocks writing slice s land on XCD s (round-robin dispatch heuristic), so each
// CSR line accumulates all its edge-writes in ONE XCD's L2 and drains once.
__global__ void scatter3s(const int* __restrict__ s0, const int* __restrict__ d0,
                          const int* __restrict__ s1, const int* __restrict__ d1,
                          const int* __restrict__ s2, const int* __restrict__ d2,
                          int e0, int e1, int e2,
                          const float* __restrict__ el, const float* __restrict__ er,
                          const int* __restrict__ off, int* __restrict__ cur,
                          int2* __restrict__ pairs, int n, int shift) {
  const int slice = blockIdx.x & (NS - 1);
  int i = (blockIdx.x >> 3) * blockDim.x + threadIdx.x;  // edge id (concatenated)
  int r, li;
  const int *sp, *dp;
  if (i < e0)                { r = 0; li = i;           sp = s0; dp = d0; }
  else if (i < e0 + e1)      { r = 1; li = i - e0;      sp = s1; dp = d1; }
  else if (i < e0 + e1 + e2) { r = 2; li = i - e0 - e1; sp = s2; dp = d2; }
  else return;
  int d = dp[li];
  if ((d >> shift) != slice) return;  // not my slice: ~7/8 of lanes exit
  int sN = sp[li];
  int gi = r * n + d;
  float v = el[(size_t)r * n + sN] + er[gi];
  v = v > 0.f ? v : NEG * v;
  int p = atomicAdd(&cur[gi], 1);
  int2 pr;
  pr.x = sN;
  pr.y = __float_as_int(v);
  pairs[off[gi] + p] = pr;
}

__global__ void scatter_pair(const int* __restrict__ src, const int* __restrict__ dst,
                             const float* __restrict__ el, const float* __restrict__ er,
                             const int* __restrict__ off_r, int* __restrict__ cur_r,
                             int2* __restrict__ pairs, int ebase, int e) {
  int i = blockIdx.x * blockDim.x + threadIdx.x;
  if (i < e) {
    int d = dst[i], sN = src[i];
    float v = el[sN] + er[d];
    v = v > 0.f ? v : NEG * v;
    int p = atomicAdd(&cur_r[d], 1);
    int2 pr;
    pr.x = sN;
    pr.y = __float_as_int(v);
    pairs[off_r[d] + p - ebase] = pr;
  }
}

// ================= per-node softmax + aggregation: half-wave per node, float2/lane =========
__device__ __forceinline__ float2 rel2(const float* __restrict__ feat,
                                       const int2* __restrict__ pairs,
                                       int beg, int end, int hl, int sl) {
  float2 acc = make_float2(0.f, 0.f);
  int deg = end - beg;
  if (deg <= 0) return acc;
  const int lbase = hl << 5;
  const int coff = sl << 1;
  float s;
  if (deg <= 32) {
    int2 pr = (sl < deg) ? pairs[beg + sl] : make_int2(0, 0xFF800000);  // pad = -inf
    float v = __int_as_float(pr.y);
    float m = v;
#pragma unroll
    for (int o = 16; o > 0; o >>= 1) m = fmaxf(m, __shfl_xor(m, o, 64));
    float a = (sl < deg) ? __expf(v - m) : 0.f;
    float t = a;
#pragma unroll
    for (int o = 16; o > 0; o >>= 1) t += __shfl_xor(t, o, 64);
    s = t;
    int j = 0, bulk = deg & ~3;
    for (; j < bulk; j += 4) {  // 4 independent gathers in flight
      int sn0 = __shfl(pr.x, lbase + j, 64);     float a0 = __shfl(a, lbase + j, 64);
      int sn1 = __shfl(pr.x, lbase + j + 1, 64); float a1 = __shfl(a, lbase + j + 1, 64);
      int sn2 = __shfl(pr.x, lbase + j + 2, 64); float a2 = __shfl(a, lbase + j + 2, 64);
      int sn3 = __shfl(pr.x, lbase + j + 3, 64); float a3 = __shfl(a, lbase + j + 3, 64);
      float2 f0 = *(const float2*)(feat + ((size_t)sn0 << 6) + coff);
      float2 f1 = *(const float2*)(feat + ((size_t)sn1 << 6) + coff);
      float2 f2 = *(const float2*)(feat + ((size_t)sn2 << 6) + coff);
      float2 f3 = *(const float2*)(feat + ((size_t)sn3 << 6) + coff);
      acc.x = fmaf(a0, f0.x, acc.x); acc.y = fmaf(a0, f0.y, acc.y);
      acc.x = fmaf(a1, f1.x, acc.x); acc.y = fmaf(a1, f1.y, acc.y);
      acc.x = fmaf(a2, f2.x, acc.x); acc.y = fmaf(a2, f2.y, acc.y);
      acc.x = fmaf(a3, f3.x, acc.x); acc.y = fmaf(a3, f3.y, acc.y);
    }
    for (; j < deg; ++j) {
      int sn = __shfl(pr.x, lbase + j, 64);
      float aj = __shfl(a, lbase + j, 64);
      float2 f = *(const float2*)(feat + ((size_t)sn << 6) + coff);
      acc.x = fmaf(aj, f.x, acc.x);
      acc.y = fmaf(aj, f.y, acc.y);
    }
  } else {
    float m = -3.4e38f;
    for (int i = beg + sl; i < end; i += 32) m = fmaxf(m, __int_as_float(pairs[i].y));
#pragma unroll
    for (int o = 16; o > 0; o >>= 1) m = fmaxf(m, __shfl_xor(m, o, 64));
    s = 0.f;
    for (int base = beg; base < end; base += 32) {
      int cm = min(32, end - base);
      int2 pr = (sl < cm) ? pairs[base + sl] : make_int2(0, 0);
      float a = (sl < cm) ? __expf(__int_as_float(pr.y) - m) : 0.f;
      float t = a;
#pragma unroll
      for (int o = 16; o > 0; o >>= 1) t += __shfl_xor(t, o, 64);
      s += t;
      for (int j = 0; j < cm; ++j) {
        int sn = __shfl(pr.x, lbase + j, 64);
        float aj = __shfl(a, lbase + j, 64);
        float2 f = *(const float2*)(feat + ((size_t)sn << 6) + coff);
        acc.x = fmaf(aj, f.x, acc.x);
        acc.y = fmaf(aj, f.y, acc.y);
      }
    }
  }
  acc.x /= s;
  acc.y /= s;
  return acc;
}

__global__ __launch_bounds__(256) void agg3(
    const float* __restrict__ feat, const int* __restrict__ off, const int2* __restrict__ pairs,
    const float* __restrict__ bias, float* __restrict__ out, int n) {
  int wave = (blockIdx.x * blockDim.x + threadIdx.x) >> 6;
  int lane = threadIdx.x & 63;
  int hl = lane >> 5, sl = lane & 31;
  int node = (wave << 1) + hl;
  if (node >= n) return;
  int o0b = off[node],         o0e = off[node + 1];
  int o1b = off[n + node],     o1e = off[n + node + 1];
  int o2b = off[2 * n + node], o2e = off[2 * n + node + 1];
  int c0 = sl << 1;
  float2 r = *(const float2*)(bias + c0);
  float2 c;
  c = rel2(feat, pairs, o0b, o0e, hl, sl);
  r.x += c.x; r.y += c.y;
  c = rel2(feat + (size_t)n * DIM, pairs, o1b, o1e, hl, sl);
  r.x += c.x; r.y += c.y;
  c = rel2(feat + (size_t)2 * n * DIM, pairs, o2b, o2e, hl, sl);
  r.x += c.x; r.y += c.y;
  *(float2*)(out + ((size_t)node << 6) + c0) = r;
}

__global__ __launch_bounds__(256) void agg1(
    const float* __restrict__ feat, const int* __restrict__ off_r,
    const int2* __restrict__ pairs, int ebase, float* __restrict__ out, int n) {
  int wave = (blockIdx.x * blockDim.x + threadIdx.x) >> 6;
  int lane = threadIdx.x & 63;
  int hl = lane >> 5, sl = lane & 31;
  int node = (wave << 1) + hl;
  if (node >= n) return;
  float2 c = rel2(feat, pairs, off_r[node] - ebase, off_r[node + 1] - ebase, hl, sl);
  float* op = out + ((size_t)node << 6) + (sl << 1);
  op[0] += c.x;
  op[1] += c.y;
}

static inline char* alignup(char* p) {
  return (char*)(((uintptr_t)p + 255) & ~(uintptr_t)255);
}

extern "C" void kernel_launch(void* const* d_in, const int* in_sizes, int n_in,
                              void* d_out, int out_size, void* d_ws, size_t ws_size,
                              hipStream_t stream) {
  const float* x = (const float*)d_in[0];
  const int n = in_sizes[0] / DIM;
  const int m = 3 * n;
  float* out = (float*)d_out;

  const int eN[3] = {in_sizes[1], in_sizes[7], in_sizes[13]};
  const int eTot = eN[0] + eN[1] + eN[2];

  const size_t featB = (size_t)n * DIM * sizeof(float);
  const size_t nB = (size_t)n * sizeof(float);

  const size_t needFused = 3 * featB + 6 * nB + 2 * (size_t)m * 4 + (size_t)(m + 2) * 4 +
                           SB * 4 + 448 * 4 + (size_t)eTot * 8 + 32 * 256;
  const bool fused = ws_size >= needFused;

  char* w = (char*)d_ws;
  float* feat = (float*)w;  w += fused ? 3 * featB : featB;  w = alignup(w);
  float* el = (float*)w;    w += fused ? 3 * nB : nB;        w = alignup(w);
  float* er = (float*)w;    w += fused ? 3 * nB : nB;        w = alignup(w);
  int* cnt = (int*)w;       w += (size_t)m * 4;              // cnt+cur contiguous (one memset)
  int* cur = (int*)w;       w += (size_t)m * 4;              w = alignup(w);
  int* off = (int*)w;       w += (size_t)(m + 1) * 4;        w = alignup(w);
  int* bsum = (int*)w;      w += SB * 4;                     w = alignup(w);
  float* qbuf = (float*)w;  w += 384 * 4;                    // 6 x 64 q-vectors
  float* bias = (float*)w;  w += 64 * 4;                     w = alignup(w);
  int2* pairs = (int2*)w;

  const int nb = (m + SB - 1) / SB;  // 293 for n=100000 (scan2 handles nb<=1024)

  hipMemsetAsync(cnt, 0, (size_t)2 * m * sizeof(int), stream);
  count3<<<(eTot + 255) / 256, 256, 0, stream>>>(
      (const int*)d_in[2], (const int*)d_in[8], (const int*)d_in[14],
      eN[0], eN[1], eN[2], cnt, n);
  scan1<<<nb, SB, 0, stream>>>(cnt, off, bsum, m);
  scan2<<<1, SB, 0, stream>>>(bsum, nb);
  scan3<<<nb, SB, 0, stream>>>(off, bsum, m);

  if (fused) {
    prep_kernel<<<7, 64, 0, stream>>>(
        (const float*)d_in[3], (const float*)d_in[9], (const float*)d_in[15],
        (const float*)d_in[4], (const float*)d_in[5],
        (const float*)d_in[10], (const float*)d_in[11],
        (const float*)d_in[16], (const float*)d_in[17],
        (const float*)d_in[6], (const float*)d_in[12], (const float*)d_in[18],
        qbuf, bias);
    elr_kernel<<<(n + 255) / 256, 256, 0, stream>>>(x, qbuf, el, er, n);
    proj3<<<(n + 4 * RPW - 1) / (4 * RPW), 256, 0, stream>>>(
        x, (const float*)d_in[3], (const float*)d_in[9], (const float*)d_in[15], feat, n);
    int shift = 0;
    while (((n - 1) >> shift) >= NS) ++shift;  // n=100000 -> shift=14 (slices 0..6)
    const int chunks = (eTot + 255) / 256;
    scatter3s<<<chunks * NS, 256, 0, stream>>>(
        (const int*)d_in[1], (const int*)d_in[2], (const int*)d_in[7], (const int*)d_in[8],
        (const int*)d_in[13], (const int*)d_in[14], eN[0], eN[1], eN[2],
        el, er, off, cur, pairs, n, shift);
    agg3<<<(n + 7) / 8, 256, 0, stream>>>(feat, off, pairs, bias, out, n);
  } else {
    init_out<<<(n * DIM + 255) / 256, 256, 0, stream>>>(
        out, (const float*)d_in[6], (const float*)d_in[12], (const float*)d_in[18], n);
    int ebase = 0;
    for (int r = 0; r < 3; ++r) {
      const int base = 1 + r * 6;
      proj_kernel<<<(n + 3) / 4, dim3(64, 4), 0, stream>>>(
          x, (const float*)d_in[base + 2], (const float*)d_in[base + 3],
          (const float*)d_in[base + 4], feat, el, er, n);
      scatter_pair<<<(eN[r] + 255) / 256, 256, 0, stream>>>(
          (const int*)d_in[base], (const int*)d_in[base + 1], el, er, off + (size_t)r * n,
          cur + (size_t)r * n, pairs, ebase, eN[r]);
      agg1<<<(n + 7) / 8, 256, 0, stream>>>(feat, off + (size_t)r * n, pairs, ebase, out, n);
      ebase += eN[r];
    }
  }
}